// Round 3
// baseline (182.845 us; speedup 1.0000x reference)
//
#include <hip/hip_runtime.h>

// ProtoNet head: N=16384 rows, C=128 classes, D=1024 dims, fp32 in/out.
// out = softmax_c( 2*dot(e[n], cent[c]) - ||cent[c]||^2 )   (sq_e dropped: softmax shift-invariant)
// cross term via split-bf16 MFMA: x=hi+lo; x*c ~= hi*chi + hi*clo + lo*chi  (K'=3072 bf16)

#define N_ROWS 16384
#define N_CLS  128
#define N_DIM  1024

// workspace layout (bytes); need 659456 B total
#define CNT_OFF 0         // int cnt[128]
#define SQC_OFF 512       // float sqc[128]
#define RL_OFF  4096      // int rowlist[128*256]
#define BHI_OFF 135168    // packed B-fragments (hi): 32 steps * 8 frags * 64 lanes * 8 bf16 = 256 KiB
#define BLO_OFF 397312    // packed B-fragments (lo), 256 KiB

typedef __attribute__((ext_vector_type(8))) short bf16x8;
typedef __attribute__((ext_vector_type(4))) float f32x4;

// ---------------- kernel 1: labels -> rowlist + counts ----------------
__global__ void k_label(const float* __restrict__ y,
                        int* __restrict__ cnt,
                        int* __restrict__ rowlist) {
    int i = blockIdx.x * blockDim.x + threadIdx.x;   // float4 index over N*C/4
    const float4* y4 = (const float4*)y;
    float4 v = y4[i];
    int base = i * 4;
    int row = base >> 7;          // / C
    int cb  = base & (N_CLS - 1); // % C
    if (v.x > 0.5f) { int s = atomicAdd(&cnt[cb + 0], 1); if (s < 256) rowlist[(cb + 0) * 256 + s] = row; }
    if (v.y > 0.5f) { int s = atomicAdd(&cnt[cb + 1], 1); if (s < 256) rowlist[(cb + 1) * 256 + s] = row; }
    if (v.z > 0.5f) { int s = atomicAdd(&cnt[cb + 2], 1); if (s < 256) rowlist[(cb + 2) * 256 + s] = row; }
    if (v.w > 0.5f) { int s = atomicAdd(&cnt[cb + 3], 1); if (s < 256) rowlist[(cb + 3) * 256 + s] = row; }
}

// ---- kernel 2: centroids -> packed bf16 hi/lo B-fragments + sq_c ----
// grid (8 d-chunks, 128 classes), 128 threads. Thread owns (class c, dim d).
// B-frag for mfma_f32_16x16x32_bf16: element j of lane l at step gs, col-frag f
//   = B[k = gs*32 + (l>>4)*8 + j][col = f*16 + (l&15)]
__global__ void k_centroid(const float* __restrict__ e,
                           const int* __restrict__ cnt,
                           const int* __restrict__ rowlist,
                           unsigned short* __restrict__ bHi,
                           unsigned short* __restrict__ bLo,
                           float* __restrict__ sqc) {
    int c  = blockIdx.y;
    int ch = blockIdx.x;
    int t  = threadIdx.x;
    int d  = ch * 128 + t;
    int n  = cnt[c];
    if (n > 256) n = 256;
    const int* rl = rowlist + c * 256;

    float acc = 0.f;
    int i = 0;
    // 8-deep MLP for HBM latency hiding
    for (; i + 8 <= n; i += 8) {
        float v0 = e[(size_t)rl[i + 0] * N_DIM + d];
        float v1 = e[(size_t)rl[i + 1] * N_DIM + d];
        float v2 = e[(size_t)rl[i + 2] * N_DIM + d];
        float v3 = e[(size_t)rl[i + 3] * N_DIM + d];
        float v4 = e[(size_t)rl[i + 4] * N_DIM + d];
        float v5 = e[(size_t)rl[i + 5] * N_DIM + d];
        float v6 = e[(size_t)rl[i + 6] * N_DIM + d];
        float v7 = e[(size_t)rl[i + 7] * N_DIM + d];
        acc += ((v0 + v1) + (v2 + v3)) + ((v4 + v5) + (v6 + v7));
    }
    for (; i < n; ++i) acc += e[(size_t)rl[i] * N_DIM + d];

    float val = (n > 0) ? acc / (float)n : 0.f;

    // split val = hi + lo (truncation split; the subtraction is exact)
    unsigned xb = __float_as_uint(val);
    unsigned short hv = (unsigned short)(xb >> 16);
    float hif = __uint_as_float(xb & 0xffff0000u);
    unsigned short lv = (unsigned short)(__float_as_uint(val - hif) >> 16);

    int gs = d >> 5;            // k-step
    int g  = (d >> 3) & 3;      // lane group
    int j  = d & 7;             // element within fragment
    int f  = c >> 4;            // col fragment
    int lb = g * 16 + (c & 15); // lane
    int idx = ((gs * 8 + f) * 64 + lb) * 8 + j;
    bHi[idx] = hv;
    bLo[idx] = lv;

    // ||centroid||^2 partial -> atomic (2 waves/block, 16 atomics/class total)
    float s = val * val;
    #pragma unroll
    for (int m = 1; m < 64; m <<= 1) s += __shfl_xor(s, m, 64);
    if ((t & 63) == 0) atomicAdd(&sqc[c], s);
}

// ------- kernel 3: split-bf16 MFMA GEMM + fused softmax --------
// 256 blocks x 256 thr (4 waves, 1 block/CU). Wave (rt, h): 32 rows
// (2 row-frags x 8 col-frags), K-half h (16 steps of 32). Partials
// combined via LDS; h=0 waves do softmax + store.
__device__ __forceinline__ void split8(const float4 a0, const float4 a1,
                                       bf16x8& hi, bf16x8& lo) {
    float v[8] = {a0.x, a0.y, a0.z, a0.w, a1.x, a1.y, a1.z, a1.w};
    #pragma unroll
    for (int j = 0; j < 8; ++j) {
        unsigned xb = __float_as_uint(v[j]);
        hi[j] = (short)(xb >> 16);
        float hif = __uint_as_float(xb & 0xffff0000u);
        lo[j] = (short)(__float_as_uint(v[j] - hif) >> 16);
    }
}

__launch_bounds__(256, 1)
__global__ void k_gemm(const float* __restrict__ e,
                       const unsigned short* __restrict__ bHiU,
                       const unsigned short* __restrict__ bLoU,
                       const float* __restrict__ sqc,
                       float* __restrict__ out) {
    __shared__ f32x4 ldsacc[2][16][64];   // 32 KiB: h=1 partials

    const bf16x8* bHi = (const bf16x8*)bHiU;
    const bf16x8* bLo = (const bf16x8*)bLoU;

    int tid  = threadIdx.x;
    int lane = tid & 63;
    int wid  = tid >> 6;
    int rt   = wid >> 1;        // row-tile within block
    int h    = wid & 1;         // K-half
    int row0 = blockIdx.x * 64 + rt * 32;
    int rlo  = lane & 15;
    int g    = lane >> 4;

    f32x4 acc[2][8];
    #pragma unroll
    for (int m = 0; m < 2; ++m)
        #pragma unroll
        for (int f = 0; f < 8; ++f)
            acc[m][f] = (f32x4)(0.f);

    // Fully unrolled: 1 wave/SIMD has no TLP — give the scheduler a flat
    // window to pipeline each step's 20 loads under the prior step's MFMAs.
    #pragma unroll
    for (int s = 0; s < 16; ++s) {
        int gs = h * 16 + s;

        // B fragments straight from L2 (same 512 KiB for every block)
        bf16x8 bh[8], bl[8];
        #pragma unroll
        for (int f = 0; f < 8; ++f) {
            int bi = (gs * 8 + f) * 64 + lane;
            bh[f] = bHi[bi];
            bl[f] = bLo[bi];
        }

        // A fp32 loaded directly in fragment layout, split to hi/lo in-reg
        bf16x8 ah[2], al[2];
        #pragma unroll
        for (int m = 0; m < 2; ++m) {
            const float* ap = e + (size_t)(row0 + m * 16 + rlo) * N_DIM + gs * 32 + g * 8;
            float4 a0 = *(const float4*)ap;
            float4 a1 = *(const float4*)(ap + 4);
            split8(a0, a1, ah[m], al[m]);
        }

        #pragma unroll
        for (int f = 0; f < 8; ++f)
            #pragma unroll
            for (int m = 0; m < 2; ++m) {
                acc[m][f] = __builtin_amdgcn_mfma_f32_16x16x32_bf16(ah[m], bh[f], acc[m][f], 0, 0, 0);
                acc[m][f] = __builtin_amdgcn_mfma_f32_16x16x32_bf16(ah[m], bl[f], acc[m][f], 0, 0, 0);
                acc[m][f] = __builtin_amdgcn_mfma_f32_16x16x32_bf16(al[m], bh[f], acc[m][f], 0, 0, 0);
            }
    }

    // combine K-halves
    if (h == 1) {
        #pragma unroll
        for (int m = 0; m < 2; ++m)
            #pragma unroll
            for (int f = 0; f < 8; ++f)
                ldsacc[rt][m * 8 + f][lane] = acc[m][f];
    }
    __syncthreads();
    if (h == 1) return;

    #pragma unroll
    for (int m = 0; m < 2; ++m)
        #pragma unroll
        for (int f = 0; f < 8; ++f)
            acc[m][f] += ldsacc[rt][m * 8 + f][lane];

    // epilogue: logits = 2*cross - sq_c ; softmax over 128 cols per row.
    // D-frag: col = f*16 + (lane&15), row = row0 + m*16 + (lane>>4)*4 + q.
    float sq[8];
    #pragma unroll
    for (int f = 0; f < 8; ++f) sq[f] = sqc[f * 16 + rlo];

    #pragma unroll
    for (int m = 0; m < 2; ++m)
        #pragma unroll
        for (int q = 0; q < 4; ++q) {
            float lg[8];
            float mx = -1e30f;
            #pragma unroll
            for (int f = 0; f < 8; ++f) {
                lg[f] = 2.f * acc[m][f][q] - sq[f];
                mx = fmaxf(mx, lg[f]);
            }
            #pragma unroll
            for (int msk = 1; msk < 16; msk <<= 1) mx = fmaxf(mx, __shfl_xor(mx, msk, 64));
            float sum = 0.f;
            #pragma unroll
            for (int f = 0; f < 8; ++f) {
                float p = __expf(lg[f] - mx);
                lg[f] = p;
                sum += p;
            }
            #pragma unroll
            for (int msk = 1; msk < 16; msk <<= 1) sum += __shfl_xor(sum, msk, 64);
            float inv = 1.f / sum;
            int row = row0 + m * 16 + g * 4 + q;
            #pragma unroll
            for (int f = 0; f < 8; ++f)
                out[(size_t)row * N_CLS + f * 16 + rlo] = lg[f] * inv;
        }
}

extern "C" void kernel_launch(void* const* d_in, const int* in_sizes, int n_in,
                              void* d_out, int out_size, void* d_ws, size_t ws_size,
                              hipStream_t stream) {
    const float* e = (const float*)d_in[0];   // embeddings [N, D]
    const float* y = (const float*)d_in[1];   // y_true [N, C]
    float* out = (float*)d_out;               // [N, C]
    char* ws = (char*)d_ws;

    int*            cnt = (int*)(ws + CNT_OFF);
    float*          sqc = (float*)(ws + SQC_OFF);
    int*            rl  = (int*)(ws + RL_OFF);
    unsigned short* bHi = (unsigned short*)(ws + BHI_OFF);
    unsigned short* bLo = (unsigned short*)(ws + BLO_OFF);

    hipMemsetAsync(ws, 0, 1024, stream);  // cnt + sqc

    hipLaunchKernelGGL(k_label, dim3((N_ROWS * N_CLS / 4) / 256), dim3(256), 0, stream,
                       y, cnt, rl);
    hipLaunchKernelGGL(k_centroid, dim3(8, N_CLS), dim3(128), 0, stream,
                       e, cnt, rl, bHi, bLo, sqc);
    hipLaunchKernelGGL(k_gemm, dim3(N_ROWS / 64), dim3(256), 0, stream,
                       e, bHi, bLo, sqc, out);
}

// Round 4
// 131.730 us; speedup vs baseline: 1.3880x; 1.3880x over previous
//
#include <hip/hip_runtime.h>

// ProtoNet head: N=16384 rows, C=128 classes, D=1024 dims, fp32 in/out.
// out = softmax_c( 2*dot(e[n], cent[c]) - ||cent[c]||^2 )  (sq_e dropped: softmax shift-invariant)
// cross term via split-bf16 MFMA: x=hi+lo; x*c ~= hi*chi + hi*clo + lo*chi  (K'=3072 bf16)

#define N_ROWS 16384
#define N_CLS  128
#define N_DIM  1024
#define CSTRIDE 32   // pad atomics: one counter per 128B cache line

// workspace layout (bytes); need ~672 KiB total
#define CNT_OFF 0         // int cnt[128*32]     (16 KiB)
#define SQC_OFF 16384     // float sqc[128*32]   (16 KiB)
#define RL_OFF  32768     // int rowlist[128*256] (128 KiB)
#define BHI_OFF 163840    // bf16 B-frags hi: 32 steps*8 frags*64 lanes*8 = 256 KiB
#define BLO_OFF 425984    // bf16 B-frags lo: 256 KiB

typedef __attribute__((ext_vector_type(8))) short bf16x8;
typedef __attribute__((ext_vector_type(4))) float f32x4;

// ---------------- kernel 1: labels -> rowlist + padded counts ----------------
__global__ void k_label(const float* __restrict__ y,
                        int* __restrict__ cnt,
                        int* __restrict__ rowlist) {
    int i = blockIdx.x * blockDim.x + threadIdx.x;   // float4 index over N*C/4
    float4 v = ((const float4*)y)[i];
    int base = i * 4;
    int row = base >> 7;          // / C
    int cb  = base & (N_CLS - 1); // % C
    if (v.x > 0.5f) { int s = atomicAdd(&cnt[(cb + 0) * CSTRIDE], 1); if (s < 256) rowlist[(cb + 0) * 256 + s] = row; }
    if (v.y > 0.5f) { int s = atomicAdd(&cnt[(cb + 1) * CSTRIDE], 1); if (s < 256) rowlist[(cb + 1) * 256 + s] = row; }
    if (v.z > 0.5f) { int s = atomicAdd(&cnt[(cb + 2) * CSTRIDE], 1); if (s < 256) rowlist[(cb + 2) * 256 + s] = row; }
    if (v.w > 0.5f) { int s = atomicAdd(&cnt[(cb + 3) * CSTRIDE], 1); if (s < 256) rowlist[(cb + 3) * 256 + s] = row; }
}

// ---- kernel 2: centroids -> packed bf16 hi/lo B-fragments + sq_c ----
// grid (8 d-chunks, 128 classes), 128 threads; thread owns (class c, dim d).
// B-frag for mfma_f32_16x16x32_bf16: elem j of lane l, step gs, col-frag f
//   = B[k = gs*32 + (l>>4)*8 + j][col = f*16 + (l&15)]
__global__ void k_centroid(const float* __restrict__ e,
                           const int* __restrict__ cnt,
                           const int* __restrict__ rowlist,
                           unsigned short* __restrict__ bHi,
                           unsigned short* __restrict__ bLo,
                           float* __restrict__ sqc) {
    int c  = blockIdx.y;
    int ch = blockIdx.x;
    int t  = threadIdx.x;
    int d  = ch * 128 + t;
    int n  = cnt[c * CSTRIDE];
    if (n > 256) n = 256;
    const int* rl = rowlist + c * 256;

    float acc = 0.f;
    int i = 0;
    // 16-deep MLP: 32 KB/CU in flight vs ~9.4 KB needed at HBM latency
    for (; i + 16 <= n; i += 16) {
        float v[16];
        #pragma unroll
        for (int u = 0; u < 16; ++u) v[u] = e[(size_t)rl[i + u] * N_DIM + d];
        float s0 = ((v[0] + v[1]) + (v[2] + v[3])) + ((v[4] + v[5]) + (v[6] + v[7]));
        float s1 = ((v[8] + v[9]) + (v[10] + v[11])) + ((v[12] + v[13]) + (v[14] + v[15]));
        acc += s0 + s1;
    }
    for (; i < n; ++i) acc += e[(size_t)rl[i] * N_DIM + d];

    float val = (n > 0) ? acc / (float)n : 0.f;

    // split val = hi + lo (truncation split; the subtraction is exact)
    unsigned xb = __float_as_uint(val);
    unsigned short hv = (unsigned short)(xb >> 16);
    float hif = __uint_as_float(xb & 0xffff0000u);
    unsigned short lv = (unsigned short)(__float_as_uint(val - hif) >> 16);

    int gs = d >> 5;            // k-step
    int g  = (d >> 3) & 3;      // lane group
    int j  = d & 7;             // element within fragment
    int f  = c >> 4;            // col fragment
    int lb = g * 16 + (c & 15); // lane
    bHi[((gs * 8 + f) * 64 + lb) * 8 + j] = hv;
    bLo[((gs * 8 + f) * 64 + lb) * 8 + j] = lv;

    // ||centroid||^2 partial -> padded atomic (16 per class)
    float s = val * val;
    #pragma unroll
    for (int m = 1; m < 64; m <<= 1) s += __shfl_xor(s, m, 64);
    if ((t & 63) == 0) atomicAdd(&sqc[c * CSTRIDE], s);
}

// ------- kernel 3: split-bf16 MFMA GEMM + fused softmax --------
// 256 blocks x 256 thr (4 waves, ~1 block/CU). Wave (rt,h): 32 rows
// (2 row-frags x 8 col-frags), K-half h (16 steps of 32). 2-deep
// ping-pong register prefetch of A+B; partials combined via LDS.
__device__ __forceinline__ void split8(const float4 a0, const float4 a1,
                                       bf16x8& hi, bf16x8& lo) {
    float v[8] = {a0.x, a0.y, a0.z, a0.w, a1.x, a1.y, a1.z, a1.w};
    #pragma unroll
    for (int j = 0; j < 8; ++j) {
        unsigned xb = __float_as_uint(v[j]);
        hi[j] = (short)(xb >> 16);
        float hif = __uint_as_float(xb & 0xffff0000u);
        lo[j] = (short)(__float_as_uint(v[j] - hif) >> 16);
    }
}

__device__ __forceinline__ void load_b(const bf16x8* __restrict__ bHi,
                                       const bf16x8* __restrict__ bLo,
                                       int gs, int lane,
                                       bf16x8 bh[8], bf16x8 bl[8]) {
    #pragma unroll
    for (int f = 0; f < 8; ++f) {
        int bi = (gs * 8 + f) * 64 + lane;
        bh[f] = bHi[bi];
        bl[f] = bLo[bi];
    }
}

__device__ __forceinline__ void load_a(const float* __restrict__ e,
                                       int row0, int rlo, int g, int gs,
                                       float4 a0[2], float4 a1[2]) {
    #pragma unroll
    for (int m = 0; m < 2; ++m) {
        const float* ap = e + (size_t)(row0 + m * 16 + rlo) * N_DIM + gs * 32 + g * 8;
        a0[m] = *(const float4*)ap;
        a1[m] = *(const float4*)(ap + 4);
    }
}

__device__ __forceinline__ void step_compute(const float4 a0[2], const float4 a1[2],
                                             const bf16x8 bh[8], const bf16x8 bl[8],
                                             f32x4 acc[2][8]) {
    bf16x8 ah[2], al[2];
    #pragma unroll
    for (int m = 0; m < 2; ++m) split8(a0[m], a1[m], ah[m], al[m]);
    #pragma unroll
    for (int f = 0; f < 8; ++f)
        #pragma unroll
        for (int m = 0; m < 2; ++m) {
            acc[m][f] = __builtin_amdgcn_mfma_f32_16x16x32_bf16(ah[m], bh[f], acc[m][f], 0, 0, 0);
            acc[m][f] = __builtin_amdgcn_mfma_f32_16x16x32_bf16(ah[m], bl[f], acc[m][f], 0, 0, 0);
            acc[m][f] = __builtin_amdgcn_mfma_f32_16x16x32_bf16(al[m], bh[f], acc[m][f], 0, 0, 0);
        }
}

__launch_bounds__(256, 1)
__global__ void k_gemm(const float* __restrict__ e,
                       const unsigned short* __restrict__ bHiU,
                       const unsigned short* __restrict__ bLoU,
                       const float* __restrict__ sqc,
                       float* __restrict__ out) {
    __shared__ f32x4 ldsacc[2][16][64];   // 32 KiB: h=1 partials

    const bf16x8* bHi = (const bf16x8*)bHiU;
    const bf16x8* bLo = (const bf16x8*)bLoU;

    int tid  = threadIdx.x;
    int lane = tid & 63;
    int wid  = tid >> 6;
    int rt   = wid >> 1;        // row-tile within block
    int h    = wid & 1;         // K-half
    int row0 = blockIdx.x * 64 + rt * 32;
    int rlo  = lane & 15;
    int g    = lane >> 4;
    int gs0  = h * 16;

    f32x4 acc[2][8];
    #pragma unroll
    for (int m = 0; m < 2; ++m)
        #pragma unroll
        for (int f = 0; f < 8; ++f)
            acc[m][f] = (f32x4)(0.f);

    bf16x8 bhA[8], blA[8], bhB[8], blB[8];
    float4 a0A[2], a1A[2], a0B[2], a1B[2];

    // prologue: step 0 into A-bufs
    load_b(bHi, bLo, gs0, lane, bhA, blA);
    load_a(e, row0, rlo, g, gs0, a0A, a1A);

    // steady state: 8 iterations x 2 steps; named ping-pong bufs only
    // (#pragma unroll 1: keep the window tight, no cross-step rename-hoist)
    #pragma unroll 1
    for (int su = 0; su < 16; su += 2) {
        load_b(bHi, bLo, gs0 + su + 1, lane, bhB, blB);      // prefetch s+1
        load_a(e, row0, rlo, g, gs0 + su + 1, a0B, a1B);
        step_compute(a0A, a1A, bhA, blA, acc);               // compute s
        if (su + 2 < 16) {
            load_b(bHi, bLo, gs0 + su + 2, lane, bhA, blA);  // prefetch s+2
            load_a(e, row0, rlo, g, gs0 + su + 2, a0A, a1A);
        }
        step_compute(a0B, a1B, bhB, blB, acc);               // compute s+1
    }

    // combine K-halves
    if (h == 1) {
        #pragma unroll
        for (int m = 0; m < 2; ++m)
            #pragma unroll
            for (int f = 0; f < 8; ++f)
                ldsacc[rt][m * 8 + f][lane] = acc[m][f];
    }
    __syncthreads();
    if (h == 1) return;

    #pragma unroll
    for (int m = 0; m < 2; ++m)
        #pragma unroll
        for (int f = 0; f < 8; ++f)
            acc[m][f] += ldsacc[rt][m * 8 + f][lane];

    // epilogue: logits = 2*cross - sq_c ; softmax over 128 cols per row.
    // D-frag: col = f*16 + (lane&15), row = row0 + m*16 + (lane>>4)*4 + q.
    float sq[8];
    #pragma unroll
    for (int f = 0; f < 8; ++f) sq[f] = sqc[(f * 16 + rlo) * CSTRIDE];

    #pragma unroll
    for (int m = 0; m < 2; ++m)
        #pragma unroll
        for (int q = 0; q < 4; ++q) {
            float lg[8];
            float mx = -1e30f;
            #pragma unroll
            for (int f = 0; f < 8; ++f) {
                lg[f] = 2.f * acc[m][f][q] - sq[f];
                mx = fmaxf(mx, lg[f]);
            }
            #pragma unroll
            for (int msk = 1; msk < 16; msk <<= 1) mx = fmaxf(mx, __shfl_xor(mx, msk, 64));
            float sum = 0.f;
            #pragma unroll
            for (int f = 0; f < 8; ++f) {
                float p = __expf(lg[f] - mx);
                lg[f] = p;
                sum += p;
            }
            #pragma unroll
            for (int msk = 1; msk < 16; msk <<= 1) sum += __shfl_xor(sum, msk, 64);
            float inv = 1.f / sum;
            int row = row0 + m * 16 + g * 4 + q;
            #pragma unroll
            for (int f = 0; f < 8; ++f)
                out[(size_t)row * N_CLS + f * 16 + rlo] = lg[f] * inv;
        }
}

extern "C" void kernel_launch(void* const* d_in, const int* in_sizes, int n_in,
                              void* d_out, int out_size, void* d_ws, size_t ws_size,
                              hipStream_t stream) {
    const float* e = (const float*)d_in[0];   // embeddings [N, D]
    const float* y = (const float*)d_in[1];   // y_true [N, C]
    float* out = (float*)d_out;               // [N, C]
    char* ws = (char*)d_ws;

    int*            cnt = (int*)(ws + CNT_OFF);
    float*          sqc = (float*)(ws + SQC_OFF);
    int*            rl  = (int*)(ws + RL_OFF);
    unsigned short* bHi = (unsigned short*)(ws + BHI_OFF);
    unsigned short* bLo = (unsigned short*)(ws + BLO_OFF);

    hipMemsetAsync(ws, 0, 32768, stream);  // padded cnt + sqc

    hipLaunchKernelGGL(k_label, dim3((N_ROWS * N_CLS / 4) / 256), dim3(256), 0, stream,
                       y, cnt, rl);
    hipLaunchKernelGGL(k_centroid, dim3(8, N_CLS), dim3(128), 0, stream,
                       e, cnt, rl, bHi, bLo, sqc);
    hipLaunchKernelGGL(k_gemm, dim3(N_ROWS / 64), dim3(256), 0, stream,
                       e, bHi, bLo, sqc, out);
}